// Round 6
// baseline (243.980 us; speedup 1.0000x reference)
//
#include <hip/hip_runtime.h>
#include <math.h>

// Problem constants (match reference)
#define B_  4
#define NQ_ 8192
#define D_  256
#define H_  8
#define L_  4
#define K_  4
#define DH_ 32
#define NV_ 5440

// Padded value-slab geometry (per (b,h)): levels with 1-px zero border
// L0: 66x66=4356, L1: 34x34=1156, L2: 18x18=324, L3: 10x10=100 -> 5936 rows
#define SLAB_ 5936

typedef short bf16x8 __attribute__((ext_vector_type(8)));
typedef float f32x4  __attribute__((ext_vector_type(4)));
typedef float f32x8  __attribute__((ext_vector_type(8)));
typedef unsigned short u16x8 __attribute__((ext_vector_type(8)));

__device__ __forceinline__ ushort f2bf(float f) {
    union { float f; unsigned u; } v; v.f = f;
    return (ushort)((v.u + 0x7FFF + ((v.u >> 16) & 1)) >> 16);
}
__device__ __forceinline__ float bf2f(ushort u) {
    union { unsigned u; float f; } v; v.u = ((unsigned)u) << 16;
    return v.f;
}
// async global->LDS 16B: per-lane global addr, wave-uniform LDS base,
// lane l lands at base + l*16 (m104 semantics). Counter: vmcnt.
__device__ __forceinline__ void gld16(const void* g, void* l) {
    __builtin_amdgcn_global_load_lds(
        (const __attribute__((address_space(1))) unsigned int*)g,
        (__attribute__((address_space(3))) unsigned int*)l, 16, 0, 0);
}

// ---------------------------------------------------------------------------
// k_prep: weight transposes ONLY (slab border zeroing lives in k_fused).
//  [0,256):   Wv transpose-convert -> Wvt
//  [256,512): Wo transpose-convert -> Wot   (Wot[n][k] = Wo[k][n])
//  [512,800): {Wt|Wf|Wlv|Wp} transpose-convert -> Wqt
// ---------------------------------------------------------------------------
__global__ __launch_bounds__(256) void k_prep(const float* __restrict__ Wv,
                                              const float* __restrict__ Wo,
                                              const float* __restrict__ Wt,
                                              const float* __restrict__ Wf,
                                              const float* __restrict__ Wlv,
                                              const float* __restrict__ Wp,
                                              ushort* __restrict__ Wvt,
                                              ushort* __restrict__ Wot,
                                              ushort* __restrict__ Wqt) {
    const int bk = blockIdx.x;
    const int t  = threadIdx.x;
    if (bk < 512) {
        const float* in; ushort* out; int n;
        if (bk < 256) { in = Wv; out = Wvt; n = bk; }
        else          { in = Wo; out = Wot; n = bk - 256; }
        out[n * 256 + t] = f2bf(in[t * 256 + n]);
    } else {
        const int n = bk - 512;
        float v;
        if (n < 64)       v = Wt[t * 64 + n];
        else if (n < 128) v = Wf[t * 64 + (n - 64)];
        else if (n < 160) v = Wlv[t * 32 + (n - 128)];
        else              v = Wp[t * 128 + (n - 160)];
        Wqt[n * 256 + t] = f2bf(v);
    }
}

// ---------------------------------------------------------------------------
// vproj role: C = value[21760][256] @ Wvt[256][256]^T + bv -> bf16 padded slab
// tile 128x128, 4 waves 2x2, 16x16x32 bf16, BK=32, T3 2-phase dbuf
// ---------------------------------------------------------------------------
__device__ __forceinline__ void vproj_role(char* smem, int fid,
                                           const float* __restrict__ value,
                                           const ushort* __restrict__ Wvt,
                                           const float* __restrict__ bv,
                                           ushort* __restrict__ vperm) {
    ushort* As0 = (ushort*)smem;             // 2 bufs x 4096 ushort (16384 B)
    ushort* Bs0 = (ushort*)(smem + 16384);   // 2 bufs x 4096 ushort (16384 B)
    const int m0   = (fid % 170) * 128;
    const int n0   = (fid / 170) * 128;
    const int t    = threadIdx.x;
    const int w    = t >> 6;
    const int lane = t & 63;
    const int wm   = (w >> 1) * 64;
    const int wn   = (w & 1) * 64;
    const int lm   = lane & 15;
    const int quad = lane >> 4;

    float4 areg[4];

    auto stageB = [&](int buf, int kc) {
        ushort* B = Bs0 + buf * 4096;
        #pragma unroll
        for (int i = 0; i < 2; ++i) {
            const int c0 = (i * 4 + w) * 64;
            const int c  = c0 + lane;
            const int row = c >> 2, ko = (c & 3) * 8;
            gld16(&Wvt[(size_t)(n0 + row) * 256 + kc + ko], B + (size_t)c0 * 8);
        }
    };
    auto loadA = [&](int kc) {
        #pragma unroll
        for (int i = 0; i < 4; ++i) {
            const int c = t + i * 256;
            const int row = c >> 3, ko = (c & 7) * 4;
            areg[i] = *(const float4*)&value[(size_t)(m0 + row) * 256 + kc + ko];
        }
    };
    auto writeA = [&](int buf) {
        ushort* A = As0 + buf * 4096;
        #pragma unroll
        for (int i = 0; i < 4; ++i) {
            const int c = t + i * 256;
            const int row = c >> 3, ko = (c & 7) * 4;
            ushort4 u;
            u.x = f2bf(areg[i].x); u.y = f2bf(areg[i].y);
            u.z = f2bf(areg[i].z); u.w = f2bf(areg[i].w);
            *(ushort4*)&A[row * 32 + ko] = u;
        }
    };

    f32x4 acc[4][4];
    #pragma unroll
    for (int i = 0; i < 4; ++i)
        #pragma unroll
        for (int j = 0; j < 4; ++j)
            acc[i][j] = (f32x4)(0.f);

    loadA(0); writeA(0);
    stageB(0, 0);
    __syncthreads();

    int cur = 0;
    for (int kc = 0; kc < 256; kc += 32) {
        const int nxt = cur ^ 1;
        const ushort* Ac = As0 + cur * 4096;
        const ushort* Bc = Bs0 + cur * 4096;
        bf16x8 af[4], bfr[4];
        #pragma unroll
        for (int mf = 0; mf < 4; ++mf)
            af[mf] = *(const bf16x8*)&Ac[(wm + mf * 16 + lm) * 32 + quad * 8];
        #pragma unroll
        for (int nf = 0; nf < 4; ++nf)
            bfr[nf] = *(const bf16x8*)&Bc[(wn + nf * 16 + lm) * 32 + quad * 8];
        if (kc + 32 < 256) {
            loadA(kc + 32);
            stageB(nxt, kc + 32);
        }
        #pragma unroll
        for (int mf = 0; mf < 4; ++mf)
            #pragma unroll
            for (int nf = 0; nf < 4; ++nf)
                acc[mf][nf] = __builtin_amdgcn_mfma_f32_16x16x32_bf16(
                    af[mf], bfr[nf], acc[mf][nf], 0, 0, 0);
        if (kc + 32 < 256) {
            writeA(nxt);
            __syncthreads();
        }
        cur = nxt;
    }

    // epilogue: bf16 padded slab write (zero-border layout)
    #pragma unroll
    for (int mf = 0; mf < 4; ++mf) {
        #pragma unroll
        for (int nf = 0; nf < 4; ++nf) {
            const f32x4 a = acc[mf][nf];
            const int col   = n0 + wn + nf * 16 + lm;
            const int rbase = m0 + wm + mf * 16 + quad * 4;
            #pragma unroll
            for (int r = 0; r < 4; ++r) {
                const int row = rbase + r;
                const float v = a[r];
                const int b = row / NV_, s = row - b * NV_;
                const int h = col >> 5, dh = col & 31;
                const int l = (s >= 5376) ? 3 : (s >= 5120) ? 2 : (s >= 4096) ? 1 : 0;
                const int lsi_[4] = {0, 4096, 5120, 5376};
                const int po_[4]  = {0, 4356, 5512, 5836};
                const int o  = s - lsi_[l];
                const int Wl = 64 >> l;
                const int y  = o >> (6 - l);
                const int x  = o & (Wl - 1);
                const int prow = po_[l] + (y + 1) * (Wl + 2) + (x + 1);
                vperm[(((size_t)(b * H_ + h)) * SLAB_ + prow) * 32 + dh] =
                    f2bf(v + bv[col]);
            }
        }
    }
}

// ---------------------------------------------------------------------------
// qproj role: query f32 -> params (fused tanh/softmax/coords epilogue)
// tile M=64 x N=288, 4 waves 2x2 (wm {0,32}, wn {0,144}), BK=32, 2-phase dbuf
// ---------------------------------------------------------------------------
__device__ __forceinline__ void qproj_role(char* smem, int fid,
                                           const float* __restrict__ query,
                                           const ushort* __restrict__ Wqt,
                                           const float* __restrict__ refpts,
                                           const float* __restrict__ bt,
                                           const float* __restrict__ bfq,
                                           const float* __restrict__ blv,
                                           const float* __restrict__ bp,
                                           float* __restrict__ params) {
    ushort* As0 = (ushort*)smem;            // 2 bufs x 2048 ushort
    ushort* Bs0 = (ushort*)(smem + 8192);   // 2 bufs x 9216 ushort
    float*  ep  = (float*)smem;             // epilogue alias (37888 B)

    const int m0   = fid * 64;
    const int t    = threadIdx.x;
    const int w    = t >> 6;
    const int lane = t & 63;
    const int wm   = (w >> 1) * 32;
    const int wn   = (w & 1) * 144;
    const int lm   = lane & 15;
    const int quad = lane >> 4;

    float4 areg[2];

    auto stageB = [&](int buf, int kc) {
        ushort* B = Bs0 + buf * 9216;
        #pragma unroll
        for (int i = 0; i < 5; ++i) {
            const int cb = i * 4 + w;
            if (cb < 18) {
                const int c0 = cb * 64;
                const int c  = c0 + lane;
                const int row = c >> 2, ko = (c & 3) * 8;
                gld16(&Wqt[(size_t)row * 256 + kc + ko], B + (size_t)c0 * 8);
            }
        }
    };
    auto loadA = [&](int kc) {
        #pragma unroll
        for (int i = 0; i < 2; ++i) {
            const int c = t + i * 256;
            const int row = c >> 3, ko = (c & 7) * 4;
            areg[i] = *(const float4*)&query[(size_t)(m0 + row) * 256 + kc + ko];
        }
    };
    auto writeA = [&](int buf) {
        ushort* A = As0 + buf * 2048;
        #pragma unroll
        for (int i = 0; i < 2; ++i) {
            const int c = t + i * 256;
            const int row = c >> 3, ko = (c & 7) * 4;
            ushort4 u;
            u.x = f2bf(areg[i].x); u.y = f2bf(areg[i].y);
            u.z = f2bf(areg[i].z); u.w = f2bf(areg[i].w);
            *(ushort4*)&A[row * 32 + ko] = u;
        }
    };

    f32x4 acc[2][9];
    #pragma unroll
    for (int i = 0; i < 2; ++i)
        #pragma unroll
        for (int j = 0; j < 9; ++j)
            acc[i][j] = (f32x4)(0.f);

    loadA(0); writeA(0);
    stageB(0, 0);
    __syncthreads();

    int cur = 0;
    for (int kc = 0; kc < 256; kc += 32) {
        const int nxt = cur ^ 1;
        const ushort* Ac = As0 + cur * 2048;
        const ushort* Bc = Bs0 + cur * 9216;
        bf16x8 af[2], bfr[9];
        #pragma unroll
        for (int mf = 0; mf < 2; ++mf)
            af[mf] = *(const bf16x8*)&Ac[(wm + mf * 16 + lm) * 32 + quad * 8];
        #pragma unroll
        for (int nf = 0; nf < 9; ++nf)
            bfr[nf] = *(const bf16x8*)&Bc[(wn + nf * 16 + lm) * 32 + quad * 8];
        if (kc + 32 < 256) {
            loadA(kc + 32);
            stageB(nxt, kc + 32);
        }
        #pragma unroll
        for (int mf = 0; mf < 2; ++mf)
            #pragma unroll
            for (int nf = 0; nf < 9; ++nf)
                acc[mf][nf] = __builtin_amdgcn_mfma_f32_16x16x32_bf16(
                    af[mf], bfr[nf], acc[mf][nf], 0, 0, 0);
        if (kc + 32 < 256) {
            writeA(nxt);
            __syncthreads();
        }
        cur = nxt;
    }

    // fused epilogue: two phases of 32 q-rows through LDS
    #pragma unroll
    for (int ph = 0; ph < 2; ++ph) {
        __syncthreads();
        if ((w >> 1) == ph) {
            #pragma unroll
            for (int mf = 0; mf < 2; ++mf)
                #pragma unroll
                for (int nf = 0; nf < 9; ++nf)
                    #pragma unroll
                    for (int r = 0; r < 4; ++r)
                        ep[(mf * 16 + quad * 4 + r) * 296 + wn + nf * 16 + lm]
                            = acc[mf][nf][r];
        }
        __syncthreads();
        #pragma unroll
        for (int it = 0; it < 4; ++it) {
            const int item = t + it * 256;
            const int qr = item >> 5;
            const int hl = item & 31;
            const int h = hl >> 2, l = hl & 3;
            const int qg = m0 + ph * 32 + qr;
            const float* lgr = &ep[qr * 296];

            const float tA = tanhf(lgr[hl * 2 + 0] + bt[hl * 2 + 0]);
            const float tB = tanhf(lgr[hl * 2 + 1] + bt[hl * 2 + 1]);
            const float fA = tanhf(lgr[64 + hl * 2 + 0] + bfq[hl * 2 + 0]);
            const float fB = tanhf(lgr[64 + hl * 2 + 1] + bfq[hl * 2 + 1]);

            const float l0 = lgr[128 + h * 4 + 0] + blv[h * 4 + 0];
            const float l1 = lgr[128 + h * 4 + 1] + blv[h * 4 + 1];
            const float l2 = lgr[128 + h * 4 + 2] + blv[h * 4 + 2];
            const float l3 = lgr[128 + h * 4 + 3] + blv[h * 4 + 3];
            const float lmx = fmaxf(fmaxf(l0, l1), fmaxf(l2, l3));
            const float e0 = __expf(l0 - lmx), e1 = __expf(l1 - lmx);
            const float e2 = __expf(l2 - lmx), e3 = __expf(l3 - lmx);
            const float lsum = e0 + e1 + e2 + e3;
            const float lwv = ((l == 0) ? e0 : (l == 1) ? e1 : (l == 2) ? e2 : e3) / lsum;

            const float p0 = lgr[160 + hl * 4 + 0] + bp[hl * 4 + 0];
            const float p1 = lgr[160 + hl * 4 + 1] + bp[hl * 4 + 1];
            const float p2 = lgr[160 + hl * 4 + 2] + bp[hl * 4 + 2];
            const float p3 = lgr[160 + hl * 4 + 3] + bp[hl * 4 + 3];
            const float pmx = fmaxf(fmaxf(p0, p1), fmaxf(p2, p3));
            const float q0e = __expf(p0 - pmx), q1e = __expf(p1 - pmx);
            const float q2e = __expf(p2 - pmx), q3e = __expf(p3 - pmx);
            const float inv = lwv / (q0e + q1e + q2e + q3e);

            const float rx = refpts[((size_t)qg * L_ + l) * 2 + 0];
            const float ry = refpts[((size_t)qg * L_ + l) * 2 + 1];
            const float Wlf = (float)(64 >> l);
            const float Hlf = (float)(64 >> l);
            const float xA = fminf(fmaxf(rx + tA / Wlf, 0.f), 1.f) * Wlf - 0.5f;
            const float xB = fminf(fmaxf(rx + tB / Wlf, 0.f), 1.f) * Wlf - 0.5f;
            const float yA = fminf(fmaxf(ry + fA / Hlf, 0.f), 1.f) * Hlf - 0.5f;
            const float yB = fminf(fmaxf(ry + fB / Hlf, 0.f), 1.f) * Hlf - 0.5f;

            float* pp = params + (size_t)qg * 256 + hl * 8;
            pp[0] = q0e * inv; pp[1] = q1e * inv; pp[2] = q2e * inv; pp[3] = q3e * inv;
            pp[4] = xA; pp[5] = xB; pp[6] = yA; pp[7] = yB;
        }
    }
}

// ---------------------------------------------------------------------------
// border role: zero the 1-px slab borders (the only part vproj doesn't write).
// ---------------------------------------------------------------------------
__device__ __forceinline__ void border_role(int fid, ushort* __restrict__ vperm) {
    const int t = threadIdx.x;
    const int p = fid * 256 + t;           // [0, 15872)
    const int bh = p / 496;
    int e = p - bh * 496;                  // cum borders: 260,392,460,496
    int l = 0;
    if (e >= 460)      { l = 3; e -= 460; }
    else if (e >= 392) { l = 2; e -= 392; }
    else if (e >= 260) { l = 1; e -= 260; }
    const int po_[4] = {0, 4356, 5512, 5836};
    const int W2 = (64 >> l) + 2;
    int row, col;
    if (e < 2 * W2) {
        row = (e < W2) ? 0 : (W2 - 1);
        col = (e < W2) ? e : (e - W2);
    } else {
        const int e2 = e - 2 * W2;
        row = 1 + (e2 >> 1);
        col = (e2 & 1) ? (W2 - 1) : 0;
    }
    uint4* dst = (uint4*)&vperm[((size_t)bh * SLAB_ + po_[l] + row * W2 + col) * 32];
    dst[0] = make_uint4(0, 0, 0, 0);
    dst[1] = make_uint4(0, 0, 0, 0);
    dst[2] = make_uint4(0, 0, 0, 0);
    dst[3] = make_uint4(0, 0, 0, 0);
}

// ---------------------------------------------------------------------------
// k_fused: vproj + qproj + border-zero in ONE launch.
//  [0,340):   vproj tiles (170 x 2)
//  [340,852): qproj tiles (512)
//  [852,914): border zeroing
// ---------------------------------------------------------------------------
__global__ __launch_bounds__(256) void k_fused(const float* __restrict__ value,
                                               const ushort* __restrict__ Wvt,
                                               const float* __restrict__ bv,
                                               ushort* __restrict__ vperm,
                                               const float* __restrict__ query,
                                               const ushort* __restrict__ Wqt,
                                               const float* __restrict__ refpts,
                                               const float* __restrict__ bt,
                                               const float* __restrict__ bfq,
                                               const float* __restrict__ blv,
                                               const float* __restrict__ bp,
                                               float* __restrict__ params) {
    __shared__ __align__(16) char smem[45056];
    const int fid = blockIdx.x;
    if (fid < 340) {
        vproj_role(smem, fid, value, Wvt, bv, vperm);
    } else if (fid < 852) {
        qproj_role(smem, fid - 340, query, Wqt, refpts, bt, bfq, blv, bp, params);
    } else {
        border_role(fid - 852, vperm);
    }
}

// ---------------------------------------------------------------------------
// k_samp (R12): sampling + attention + output projection, defects fixed.
// R5 failure analysis: (a) S reads at 528B stride = 8-way bank conflict
// (1.57M SQ_LDS_BANK_CONFLICT); (b) Wot staged through LDS with 8 barriers.
// Fixes: (a) S rows exactly 512B with 16B-unit XOR swizzle (addr ^= (q&7)<<4)
// -- per-8-lane phase covers all 32 banks on both write and read (T2);
// (b) B-fragments loaded straight global->reg (Wot 128KB, L2-resident),
// ZERO barriers in the GEMM phase, one barrier total to publish S.
// Phase 1 identical to R1-proven k_sample (per-thread code unchanged).
// XCD swizzle: b=(fid&7)>>1 keeps one batch's slab per XCD (L2-resident).
// ---------------------------------------------------------------------------
__global__ __launch_bounds__(512) void k_samp(const ushort* __restrict__ vperm,
                                              const float* __restrict__ params,
                                              const ushort* __restrict__ Wot,
                                              const float* __restrict__ bo,
                                              float* __restrict__ outp) {
    __shared__ float  pm[16][264];                 // 16,896 B
    __shared__ __align__(16) ushort S[16 * 256];   //  8,192 B (512 B rows)
    const int fid = blockIdx.x;
    const int b   = (fid & 7) >> 1;
    const int q0  = (((fid >> 3) << 1) | (fid & 1)) * 16;
    const int t   = threadIdx.x;
    const int ql  = t >> 5;        // 0..15
    const int sub = t & 31;
    const int h   = sub >> 2;
    const int dh8 = sub & 3;

    for (int i = t; i < 16 * 256; i += 512) {
        const int q = i >> 8, c = i & 255;
        pm[q][(c >> 5) * 33 + (c & 31)] = params[((size_t)(b * NQ_ + q0 + q)) * 256 + c];
    }
    __syncthreads();

    const ushort* vb = vperm + ((size_t)(b * H_ + h)) * SLAB_ * 32 + dh8 * 8;
    const int po_[4] = {0, 4356, 5512, 5836};

    f32x8 acc = (f32x8)(0.f);
    #pragma unroll
    for (int l = 0; l < L_; ++l) {
        const int W2 = (64 >> l) + 2;
        const ushort* vl = vb + (size_t)po_[l] * 32;
        const float* p  = &pm[ql][h * 33 + l * 8];
        const float a0 = p[0], a1 = p[1], a2 = p[2], a3 = p[3];
        const float xA = p[4], xB = p[5], yA = p[6], yB = p[7];
        const float xa0 = floorf(xA), xb0 = floorf(xB);
        const float ya0 = floorf(yA), yb0 = floorf(yB);
        const float fxa = xA - xa0, fxb = xB - xb0;
        const float fya = yA - ya0, fyb = yB - yb0;
        const int pxa = (int)xa0 + 1, pxb = (int)xb0 + 1;
        const int pya = (int)ya0 + 1, pyb = (int)yb0 + 1;
        #pragma unroll
        for (int k = 0; k < 4; ++k) {
            const int   px = (k & 2) ? pxb : pxa;
            const int   py = (k & 1) ? pyb : pya;
            const float fx = (k & 2) ? fxb : fxa;
            const float fy = (k & 1) ? fyb : fya;
            const float ak = (k == 0) ? a0 : (k == 1) ? a1 : (k == 2) ? a2 : a3;
            const ushort* cp = vl + (size_t)(py * W2 + px) * 32;
            const u16x8 u00 = *(const u16x8*)cp;
            const u16x8 u10 = *(const u16x8*)(cp + 32);
            const u16x8 u01 = *(const u16x8*)(cp + W2 * 32);
            const u16x8 u11 = *(const u16x8*)(cp + (W2 + 1) * 32);
            const float gx = 1.f - fx, gy = 1.f - fy;
            const float w00 = ak * gx * gy, w10 = ak * fx * gy;
            const float w01 = ak * gx * fy, w11 = ak * fx * fy;
            #pragma unroll
            for (int e = 0; e < 8; ++e)
                acc[e] += bf2f(u00[e]) * w00 + bf2f(u10[e]) * w10
                        + bf2f(u01[e]) * w01 + bf2f(u11[e]) * w11;
        }
    }
    u16x8 o;
    #pragma unroll
    for (int e = 0; e < 8; ++e) o[e] = f2bf(acc[e]);
    // swizzled S write: row ql (512 B), chunk sub, addr ^= (ql&7)<<4
    *(u16x8*)((char*)S + ql * 512 + ((sub * 16) ^ ((ql & 7) << 4))) = o;

    __syncthreads();   // publish S (the ONLY barrier in phase 2)

    // ---- phase 2: out[16][256] = S @ Wot^T + bo; B-frags global->reg
    const int w    = t >> 6;       // 0..7
    const int lane = t & 63;
    const int lm   = lane & 15;
    const int quad = lane >> 4;
    const int wn   = w * 32;

    f32x4 oacc[2];
    oacc[0] = (f32x4)(0.f);
    oacc[1] = (f32x4)(0.f);

    const char* Srow = (const char*)S + lm * 512;
    const int sswz = (lm & 7) << 4;
    #pragma unroll
    for (int st = 0; st < 8; ++st) {           // kc = st*32
        const int kc = st * 32;
        const int chunk = st * 4 + quad;       // 16B chunk index in row
        const bf16x8 af = *(const bf16x8*)(Srow + ((chunk << 4) ^ sswz));
        const bf16x8 b0 = *(const bf16x8*)&Wot[(size_t)(wn + lm) * 256 + kc + quad * 8];
        const bf16x8 b1 = *(const bf16x8*)&Wot[(size_t)(wn + 16 + lm) * 256 + kc + quad * 8];
        oacc[0] = __builtin_amdgcn_mfma_f32_16x16x32_bf16(af, b0, oacc[0], 0, 0, 0);
        oacc[1] = __builtin_amdgcn_mfma_f32_16x16x32_bf16(af, b1, oacc[1], 0, 0, 0);
    }

    #pragma unroll
    for (int nf = 0; nf < 2; ++nf) {
        const int col = wn + nf * 16 + lm;
        const float bb = bo[col];
        #pragma unroll
        for (int r = 0; r < 4; ++r) {
            const int qr = quad * 4 + r;
            outp[((size_t)(b * NQ_ + q0 + qr)) * 256 + col] = oacc[nf][r] + bb;
        }
    }
}

// ---------------------------------------------------------------------------
extern "C" void kernel_launch(void* const* d_in, const int* in_sizes, int n_in,
                              void* d_out, int out_size, void* d_ws, size_t ws_size,
                              hipStream_t stream) {
    const float* query = (const float*)d_in[0];
    const float* refp  = (const float*)d_in[1];
    const float* value = (const float*)d_in[2];
    const float* Wt = (const float*)d_in[5];
    const float* bt = (const float*)d_in[6];
    const float* Wf = (const float*)d_in[7];
    const float* bf = (const float*)d_in[8];
    const float* Wl = (const float*)d_in[9];
    const float* bl = (const float*)d_in[10];
    const float* Wp = (const float*)d_in[11];
    const float* bp = (const float*)d_in[12];
    const float* Wv = (const float*)d_in[13];
    const float* bv = (const float*)d_in[14];
    const float* Wo = (const float*)d_in[15];
    const float* bo = (const float*)d_in[16];

    // ws layout (all offsets 16B aligned)
    char* wsb = (char*)d_ws;
    ushort* vperm  = (ushort*)wsb;                       // 12,156,928 B
    float*  params = (float*)(wsb + 12156928);           // 33,554,432 B
    ushort* Wvt    = (ushort*)(wsb + 62488576);          // 131,072 B
    ushort* Wot    = (ushort*)(wsb + 62619648);          // 131,072 B
    ushort* Wqt    = (ushort*)(wsb + 62750720);          // 147,456 B

    // weight transposes
    k_prep<<<800, 256, 0, stream>>>(Wv, Wo, Wt, Wf, Wl, Wp, Wvt, Wot, Wqt);
    // fused: vproj (340) + qproj (512) + slab border zero (62)
    k_fused<<<914, 256, 0, stream>>>(value, Wvt, bv, vperm,
                                     query, Wqt, refp, bt, bf, bl, bp, params);
    // sampling + attention + output projection (XCD-swizzled flat grid)
    k_samp<<<2048, 512, 0, stream>>>(vperm, params, Wot, bo, (float*)d_out);
}

// Round 7
// 235.001 us; speedup vs baseline: 1.0382x; 1.0382x over previous
//
#include <hip/hip_runtime.h>
#include <math.h>

// Problem constants (match reference)
#define B_  4
#define NQ_ 8192
#define D_  256
#define H_  8
#define L_  4
#define K_  4
#define DH_ 32
#define NV_ 5440

// Padded value-slab geometry (per (b,h)): levels with 1-px zero border
// L0: 66x66=4356, L1: 34x34=1156, L2: 18x18=324, L3: 10x10=100 -> 5936 rows
#define SLAB_ 5936

typedef short bf16x8 __attribute__((ext_vector_type(8)));
typedef float f32x4  __attribute__((ext_vector_type(4)));
typedef float f32x8  __attribute__((ext_vector_type(8)));
typedef unsigned short u16x8 __attribute__((ext_vector_type(8)));

__device__ __forceinline__ ushort f2bf(float f) {
    union { float f; unsigned u; } v; v.f = f;
    return (ushort)((v.u + 0x7FFF + ((v.u >> 16) & 1)) >> 16);
}
__device__ __forceinline__ float bf2f(ushort u) {
    union { unsigned u; float f; } v; v.u = ((unsigned)u) << 16;
    return v.f;
}
// async global->LDS 16B: per-lane global addr, wave-uniform LDS base,
// lane l lands at base + l*16 (m104 semantics). Counter: vmcnt.
__device__ __forceinline__ void gld16(const void* g, void* l) {
    __builtin_amdgcn_global_load_lds(
        (const __attribute__((address_space(1))) unsigned int*)g,
        (__attribute__((address_space(3))) unsigned int*)l, 16, 0, 0);
}

// ---------------------------------------------------------------------------
// k_prep: weight transposes ONLY (slab border zeroing lives in k_fused).
//  [0,256):   Wv transpose-convert -> Wvt
//  [256,512): Wo transpose-convert -> Wot   (Wot[n][k] = Wo[k][n])
//  [512,800): {Wt|Wf|Wlv|Wp} transpose-convert -> Wqt
// ---------------------------------------------------------------------------
__global__ __launch_bounds__(256) void k_prep(const float* __restrict__ Wv,
                                              const float* __restrict__ Wo,
                                              const float* __restrict__ Wt,
                                              const float* __restrict__ Wf,
                                              const float* __restrict__ Wlv,
                                              const float* __restrict__ Wp,
                                              ushort* __restrict__ Wvt,
                                              ushort* __restrict__ Wot,
                                              ushort* __restrict__ Wqt) {
    const int bk = blockIdx.x;
    const int t  = threadIdx.x;
    if (bk < 512) {
        const float* in; ushort* out; int n;
        if (bk < 256) { in = Wv; out = Wvt; n = bk; }
        else          { in = Wo; out = Wot; n = bk - 256; }
        out[n * 256 + t] = f2bf(in[t * 256 + n]);
    } else {
        const int n = bk - 512;
        float v;
        if (n < 64)       v = Wt[t * 64 + n];
        else if (n < 128) v = Wf[t * 64 + (n - 64)];
        else if (n < 160) v = Wlv[t * 32 + (n - 128)];
        else              v = Wp[t * 128 + (n - 160)];
        Wqt[n * 256 + t] = f2bf(v);
    }
}

// ---------------------------------------------------------------------------
// vproj role: C = value[21760][256] @ Wvt[256][256]^T + bv -> bf16 padded slab
// tile 128x128, 4 waves 2x2, 16x16x32 bf16, BK=32, T3 2-phase dbuf
// ---------------------------------------------------------------------------
__device__ __forceinline__ void vproj_role(char* smem, int fid,
                                           const float* __restrict__ value,
                                           const ushort* __restrict__ Wvt,
                                           const float* __restrict__ bv,
                                           ushort* __restrict__ vperm) {
    ushort* As0 = (ushort*)smem;             // 2 bufs x 4096 ushort (16384 B)
    ushort* Bs0 = (ushort*)(smem + 16384);   // 2 bufs x 4096 ushort (16384 B)
    const int m0   = (fid % 170) * 128;
    const int n0   = (fid / 170) * 128;
    const int t    = threadIdx.x;
    const int w    = t >> 6;
    const int lane = t & 63;
    const int wm   = (w >> 1) * 64;
    const int wn   = (w & 1) * 64;
    const int lm   = lane & 15;
    const int quad = lane >> 4;

    float4 areg[4];

    auto stageB = [&](int buf, int kc) {
        ushort* B = Bs0 + buf * 4096;
        #pragma unroll
        for (int i = 0; i < 2; ++i) {
            const int c0 = (i * 4 + w) * 64;
            const int c  = c0 + lane;
            const int row = c >> 2, ko = (c & 3) * 8;
            gld16(&Wvt[(size_t)(n0 + row) * 256 + kc + ko], B + (size_t)c0 * 8);
        }
    };
    auto loadA = [&](int kc) {
        #pragma unroll
        for (int i = 0; i < 4; ++i) {
            const int c = t + i * 256;
            const int row = c >> 3, ko = (c & 7) * 4;
            areg[i] = *(const float4*)&value[(size_t)(m0 + row) * 256 + kc + ko];
        }
    };
    auto writeA = [&](int buf) {
        ushort* A = As0 + buf * 4096;
        #pragma unroll
        for (int i = 0; i < 4; ++i) {
            const int c = t + i * 256;
            const int row = c >> 3, ko = (c & 7) * 4;
            ushort4 u;
            u.x = f2bf(areg[i].x); u.y = f2bf(areg[i].y);
            u.z = f2bf(areg[i].z); u.w = f2bf(areg[i].w);
            *(ushort4*)&A[row * 32 + ko] = u;
        }
    };

    f32x4 acc[4][4];
    #pragma unroll
    for (int i = 0; i < 4; ++i)
        #pragma unroll
        for (int j = 0; j < 4; ++j)
            acc[i][j] = (f32x4)(0.f);

    loadA(0); writeA(0);
    stageB(0, 0);
    __syncthreads();

    int cur = 0;
    for (int kc = 0; kc < 256; kc += 32) {
        const int nxt = cur ^ 1;
        const ushort* Ac = As0 + cur * 4096;
        const ushort* Bc = Bs0 + cur * 4096;
        bf16x8 af[4], bfr[4];
        #pragma unroll
        for (int mf = 0; mf < 4; ++mf)
            af[mf] = *(const bf16x8*)&Ac[(wm + mf * 16 + lm) * 32 + quad * 8];
        #pragma unroll
        for (int nf = 0; nf < 4; ++nf)
            bfr[nf] = *(const bf16x8*)&Bc[(wn + nf * 16 + lm) * 32 + quad * 8];
        if (kc + 32 < 256) {
            loadA(kc + 32);
            stageB(nxt, kc + 32);
        }
        #pragma unroll
        for (int mf = 0; mf < 4; ++mf)
            #pragma unroll
            for (int nf = 0; nf < 4; ++nf)
                acc[mf][nf] = __builtin_amdgcn_mfma_f32_16x16x32_bf16(
                    af[mf], bfr[nf], acc[mf][nf], 0, 0, 0);
        if (kc + 32 < 256) {
            writeA(nxt);
            __syncthreads();
        }
        cur = nxt;
    }

    // epilogue: bf16 padded slab write (zero-border layout)
    #pragma unroll
    for (int mf = 0; mf < 4; ++mf) {
        #pragma unroll
        for (int nf = 0; nf < 4; ++nf) {
            const f32x4 a = acc[mf][nf];
            const int col   = n0 + wn + nf * 16 + lm;
            const int rbase = m0 + wm + mf * 16 + quad * 4;
            #pragma unroll
            for (int r = 0; r < 4; ++r) {
                const int row = rbase + r;
                const float v = a[r];
                const int b = row / NV_, s = row - b * NV_;
                const int h = col >> 5, dh = col & 31;
                const int l = (s >= 5376) ? 3 : (s >= 5120) ? 2 : (s >= 4096) ? 1 : 0;
                const int lsi_[4] = {0, 4096, 5120, 5376};
                const int po_[4]  = {0, 4356, 5512, 5836};
                const int o  = s - lsi_[l];
                const int Wl = 64 >> l;
                const int y  = o >> (6 - l);
                const int x  = o & (Wl - 1);
                const int prow = po_[l] + (y + 1) * (Wl + 2) + (x + 1);
                vperm[(((size_t)(b * H_ + h)) * SLAB_ + prow) * 32 + dh] =
                    f2bf(v + bv[col]);
            }
        }
    }
}

// ---------------------------------------------------------------------------
// qproj role: query f32 -> params (fused tanh/softmax/coords epilogue)
// tile M=64 x N=288, 4 waves 2x2 (wm {0,32}, wn {0,144}), BK=32, 2-phase dbuf
// ---------------------------------------------------------------------------
__device__ __forceinline__ void qproj_role(char* smem, int fid,
                                           const float* __restrict__ query,
                                           const ushort* __restrict__ Wqt,
                                           const float* __restrict__ refpts,
                                           const float* __restrict__ bt,
                                           const float* __restrict__ bfq,
                                           const float* __restrict__ blv,
                                           const float* __restrict__ bp,
                                           float* __restrict__ params) {
    ushort* As0 = (ushort*)smem;            // 2 bufs x 2048 ushort
    ushort* Bs0 = (ushort*)(smem + 8192);   // 2 bufs x 9216 ushort
    float*  ep  = (float*)smem;             // epilogue alias (37888 B)

    const int m0   = fid * 64;
    const int t    = threadIdx.x;
    const int w    = t >> 6;
    const int lane = t & 63;
    const int wm   = (w >> 1) * 32;
    const int wn   = (w & 1) * 144;
    const int lm   = lane & 15;
    const int quad = lane >> 4;

    float4 areg[2];

    auto stageB = [&](int buf, int kc) {
        ushort* B = Bs0 + buf * 9216;
        #pragma unroll
        for (int i = 0; i < 5; ++i) {
            const int cb = i * 4 + w;
            if (cb < 18) {
                const int c0 = cb * 64;
                const int c  = c0 + lane;
                const int row = c >> 2, ko = (c & 3) * 8;
                gld16(&Wqt[(size_t)row * 256 + kc + ko], B + (size_t)c0 * 8);
            }
        }
    };
    auto loadA = [&](int kc) {
        #pragma unroll
        for (int i = 0; i < 2; ++i) {
            const int c = t + i * 256;
            const int row = c >> 3, ko = (c & 7) * 4;
            areg[i] = *(const float4*)&query[(size_t)(m0 + row) * 256 + kc + ko];
        }
    };
    auto writeA = [&](int buf) {
        ushort* A = As0 + buf * 2048;
        #pragma unroll
        for (int i = 0; i < 2; ++i) {
            const int c = t + i * 256;
            const int row = c >> 3, ko = (c & 7) * 4;
            ushort4 u;
            u.x = f2bf(areg[i].x); u.y = f2bf(areg[i].y);
            u.z = f2bf(areg[i].z); u.w = f2bf(areg[i].w);
            *(ushort4*)&A[row * 32 + ko] = u;
        }
    };

    f32x4 acc[2][9];
    #pragma unroll
    for (int i = 0; i < 2; ++i)
        #pragma unroll
        for (int j = 0; j < 9; ++j)
            acc[i][j] = (f32x4)(0.f);

    loadA(0); writeA(0);
    stageB(0, 0);
    __syncthreads();

    int cur = 0;
    for (int kc = 0; kc < 256; kc += 32) {
        const int nxt = cur ^ 1;
        const ushort* Ac = As0 + cur * 2048;
        const ushort* Bc = Bs0 + cur * 9216;
        bf16x8 af[2], bfr[9];
        #pragma unroll
        for (int mf = 0; mf < 2; ++mf)
            af[mf] = *(const bf16x8*)&Ac[(wm + mf * 16 + lm) * 32 + quad * 8];
        #pragma unroll
        for (int nf = 0; nf < 9; ++nf)
            bfr[nf] = *(const bf16x8*)&Bc[(wn + nf * 16 + lm) * 32 + quad * 8];
        if (kc + 32 < 256) {
            loadA(kc + 32);
            stageB(nxt, kc + 32);
        }
        #pragma unroll
        for (int mf = 0; mf < 2; ++mf)
            #pragma unroll
            for (int nf = 0; nf < 9; ++nf)
                acc[mf][nf] = __builtin_amdgcn_mfma_f32_16x16x32_bf16(
                    af[mf], bfr[nf], acc[mf][nf], 0, 0, 0);
        if (kc + 32 < 256) {
            writeA(nxt);
            __syncthreads();
        }
        cur = nxt;
    }

    // fused epilogue: two phases of 32 q-rows through LDS
    #pragma unroll
    for (int ph = 0; ph < 2; ++ph) {
        __syncthreads();
        if ((w >> 1) == ph) {
            #pragma unroll
            for (int mf = 0; mf < 2; ++mf)
                #pragma unroll
                for (int nf = 0; nf < 9; ++nf)
                    #pragma unroll
                    for (int r = 0; r < 4; ++r)
                        ep[(mf * 16 + quad * 4 + r) * 296 + wn + nf * 16 + lm]
                            = acc[mf][nf][r];
        }
        __syncthreads();
        #pragma unroll
        for (int it = 0; it < 4; ++it) {
            const int item = t + it * 256;
            const int qr = item >> 5;
            const int hl = item & 31;
            const int h = hl >> 2, l = hl & 3;
            const int qg = m0 + ph * 32 + qr;
            const float* lgr = &ep[qr * 296];

            const float tA = tanhf(lgr[hl * 2 + 0] + bt[hl * 2 + 0]);
            const float tB = tanhf(lgr[hl * 2 + 1] + bt[hl * 2 + 1]);
            const float fA = tanhf(lgr[64 + hl * 2 + 0] + bfq[hl * 2 + 0]);
            const float fB = tanhf(lgr[64 + hl * 2 + 1] + bfq[hl * 2 + 1]);

            const float l0 = lgr[128 + h * 4 + 0] + blv[h * 4 + 0];
            const float l1 = lgr[128 + h * 4 + 1] + blv[h * 4 + 1];
            const float l2 = lgr[128 + h * 4 + 2] + blv[h * 4 + 2];
            const float l3 = lgr[128 + h * 4 + 3] + blv[h * 4 + 3];
            const float lmx = fmaxf(fmaxf(l0, l1), fmaxf(l2, l3));
            const float e0 = __expf(l0 - lmx), e1 = __expf(l1 - lmx);
            const float e2 = __expf(l2 - lmx), e3 = __expf(l3 - lmx);
            const float lsum = e0 + e1 + e2 + e3;
            const float lwv = ((l == 0) ? e0 : (l == 1) ? e1 : (l == 2) ? e2 : e3) / lsum;

            const float p0 = lgr[160 + hl * 4 + 0] + bp[hl * 4 + 0];
            const float p1 = lgr[160 + hl * 4 + 1] + bp[hl * 4 + 1];
            const float p2 = lgr[160 + hl * 4 + 2] + bp[hl * 4 + 2];
            const float p3 = lgr[160 + hl * 4 + 3] + bp[hl * 4 + 3];
            const float pmx = fmaxf(fmaxf(p0, p1), fmaxf(p2, p3));
            const float q0e = __expf(p0 - pmx), q1e = __expf(p1 - pmx);
            const float q2e = __expf(p2 - pmx), q3e = __expf(p3 - pmx);
            const float inv = lwv / (q0e + q1e + q2e + q3e);

            const float rx = refpts[((size_t)qg * L_ + l) * 2 + 0];
            const float ry = refpts[((size_t)qg * L_ + l) * 2 + 1];
            const float Wlf = (float)(64 >> l);
            const float Hlf = (float)(64 >> l);
            const float xA = fminf(fmaxf(rx + tA / Wlf, 0.f), 1.f) * Wlf - 0.5f;
            const float xB = fminf(fmaxf(rx + tB / Wlf, 0.f), 1.f) * Wlf - 0.5f;
            const float yA = fminf(fmaxf(ry + fA / Hlf, 0.f), 1.f) * Hlf - 0.5f;
            const float yB = fminf(fmaxf(ry + fB / Hlf, 0.f), 1.f) * Hlf - 0.5f;

            float* pp = params + (size_t)qg * 256 + hl * 8;
            pp[0] = q0e * inv; pp[1] = q1e * inv; pp[2] = q2e * inv; pp[3] = q3e * inv;
            pp[4] = xA; pp[5] = xB; pp[6] = yA; pp[7] = yB;
        }
    }
}

// ---------------------------------------------------------------------------
// border role: zero the 1-px slab borders (the only part vproj doesn't write).
// ---------------------------------------------------------------------------
__device__ __forceinline__ void border_role(int fid, ushort* __restrict__ vperm) {
    const int t = threadIdx.x;
    const int p = fid * 256 + t;           // [0, 15872)
    const int bh = p / 496;
    int e = p - bh * 496;                  // cum borders: 260,392,460,496
    int l = 0;
    if (e >= 460)      { l = 3; e -= 460; }
    else if (e >= 392) { l = 2; e -= 392; }
    else if (e >= 260) { l = 1; e -= 260; }
    const int po_[4] = {0, 4356, 5512, 5836};
    const int W2 = (64 >> l) + 2;
    int row, col;
    if (e < 2 * W2) {
        row = (e < W2) ? 0 : (W2 - 1);
        col = (e < W2) ? e : (e - W2);
    } else {
        const int e2 = e - 2 * W2;
        row = 1 + (e2 >> 1);
        col = (e2 & 1) ? (W2 - 1) : 0;
    }
    uint4* dst = (uint4*)&vperm[((size_t)bh * SLAB_ + po_[l] + row * W2 + col) * 32];
    dst[0] = make_uint4(0, 0, 0, 0);
    dst[1] = make_uint4(0, 0, 0, 0);
    dst[2] = make_uint4(0, 0, 0, 0);
    dst[3] = make_uint4(0, 0, 0, 0);
}

// ---------------------------------------------------------------------------
// k_fused: vproj + qproj + border-zero in ONE launch.
//  [0,340):   vproj tiles (170 x 2)
//  [340,852): qproj tiles (512)
//  [852,914): border zeroing
// ---------------------------------------------------------------------------
__global__ __launch_bounds__(256) void k_fused(const float* __restrict__ value,
                                               const ushort* __restrict__ Wvt,
                                               const float* __restrict__ bv,
                                               ushort* __restrict__ vperm,
                                               const float* __restrict__ query,
                                               const ushort* __restrict__ Wqt,
                                               const float* __restrict__ refpts,
                                               const float* __restrict__ bt,
                                               const float* __restrict__ bfq,
                                               const float* __restrict__ blv,
                                               const float* __restrict__ bp,
                                               float* __restrict__ params) {
    __shared__ __align__(16) char smem[45056];
    const int fid = blockIdx.x;
    if (fid < 340) {
        vproj_role(smem, fid, value, Wvt, bv, vperm);
    } else if (fid < 852) {
        qproj_role(smem, fid - 340, query, Wqt, refpts, bt, bfq, blv, bp, params);
    } else {
        border_role(fid - 852, vperm);
    }
}

// ---------------------------------------------------------------------------
// k_sample (R13): bilinear sampling + attention -> bf16 mid.
// Level-split: thread = (ql, h, dh8, lhalf); 512 threads / 8 queries per
// block, one query per wave. Each thread gathers 2 levels x 4 taps (32
// independent 16B loads -- per-thread MLP preserved, unlike R2), then a
// single 8-elem __shfl_xor(32) pair-reduce combines the level halves and
// the lh==0 half-wave writes. Mechanism: halves per-wave dependent work,
// doubles wave count -> better latency overlap (R1 diagnosis: latency-bound,
// VALU 50%, HBM 11%, occ 19%).
// XCD swizzle: b=(fid&7)>>1 keeps one batch's slab per XCD (L2-resident,
// FETCH 61->34.9 MB confirmed). R5/R6 out-proj fusion abandoned: M=16 GEMM
// per block re-reads all of Wot (4x L2 traffic) serialized behind sampling.
// ---------------------------------------------------------------------------
__global__ __launch_bounds__(512) void k_sample(const ushort* __restrict__ vperm,
                                                const float* __restrict__ params,
                                                ushort* __restrict__ mid) {
    __shared__ float pm[8][264];   // per q: [h][33] padded
    const int fid = blockIdx.x;
    const int b   = (fid & 7) >> 1;
    const int q0  = (((fid >> 3) << 1) | (fid & 1)) * 8;
    const int t   = threadIdx.x;
    const int ql  = t >> 6;        // 0..7, one query per wave
    const int l6  = t & 63;
    const int lh  = l6 >> 5;       // level half: 0 -> l in {0,1}, 1 -> {2,3}
    const int sub = l6 & 31;
    const int h   = sub >> 2;
    const int dh8 = sub & 3;

    for (int i = t; i < 8 * 256; i += 512) {
        const int q = i >> 8, c = i & 255;
        pm[q][(c >> 5) * 33 + (c & 31)] = params[((size_t)(b * NQ_ + q0 + q)) * 256 + c];
    }
    __syncthreads();

    const ushort* vb = vperm + ((size_t)(b * H_ + h)) * SLAB_ * 32 + dh8 * 8;

    f32x8 acc = (f32x8)(0.f);
    #pragma unroll
    for (int li = 0; li < 2; ++li) {
        const int l  = lh * 2 + li;               // per-lane value, no branch
        const int W2 = (64 >> l) + 2;
        const int po = (l == 0) ? 0 : (l == 1) ? 4356 : (l == 2) ? 5512 : 5836;
        const ushort* vl = vb + (size_t)po * 32;
        const float* p  = &pm[ql][h * 33 + l * 8];
        const float a0 = p[0], a1 = p[1], a2 = p[2], a3 = p[3];
        const float xA = p[4], xB = p[5], yA = p[6], yB = p[7];
        const float xa0 = floorf(xA), xb0 = floorf(xB);
        const float ya0 = floorf(yA), yb0 = floorf(yB);
        const float fxa = xA - xa0, fxb = xB - xb0;
        const float fya = yA - ya0, fyb = yB - yb0;
        const int pxa = (int)xa0 + 1, pxb = (int)xb0 + 1;
        const int pya = (int)ya0 + 1, pyb = (int)yb0 + 1;
        #pragma unroll
        for (int k = 0; k < 4; ++k) {
            const int   px = (k & 2) ? pxb : pxa;
            const int   py = (k & 1) ? pyb : pya;
            const float fx = (k & 2) ? fxb : fxa;
            const float fy = (k & 1) ? fyb : fya;
            const float ak = (k == 0) ? a0 : (k == 1) ? a1 : (k == 2) ? a2 : a3;
            const ushort* cp = vl + (size_t)(py * W2 + px) * 32;
            const u16x8 u00 = *(const u16x8*)cp;
            const u16x8 u10 = *(const u16x8*)(cp + 32);
            const u16x8 u01 = *(const u16x8*)(cp + W2 * 32);
            const u16x8 u11 = *(const u16x8*)(cp + (W2 + 1) * 32);
            const float gx = 1.f - fx, gy = 1.f - fy;
            const float w00 = ak * gx * gy, w10 = ak * fx * gy;
            const float w01 = ak * gx * fy, w11 = ak * fx * fy;
            #pragma unroll
            for (int e = 0; e < 8; ++e)
                acc[e] += bf2f(u00[e]) * w00 + bf2f(u10[e]) * w10
                        + bf2f(u01[e]) * w01 + bf2f(u11[e]) * w11;
        }
    }
    // combine level halves across lane bit 5: (l0+l1) + (l2+l3)
    #pragma unroll
    for (int e = 0; e < 8; ++e)
        acc[e] += __shfl_xor(acc[e], 32);
    if (lh == 0) {
        u16x8 o;
        #pragma unroll
        for (int e = 0; e < 8; ++e) o[e] = f2bf(acc[e]);
        *(u16x8*)&mid[((size_t)(b * NQ_ + q0 + ql)) * 256 + sub * 8] = o;
    }
}

// ---------------------------------------------------------------------------
// out projection: C = mid[32768][256] @ Wot[256][256]^T + bo -> f32 out
// tile 128x128, T3 2-phase dbuf, gload_lds both operands (bf16 A)
// ---------------------------------------------------------------------------
__global__ __launch_bounds__(256) void k_ogemm(const ushort* __restrict__ A,
                                               const ushort* __restrict__ Bt,
                                               const float* __restrict__ bias,
                                               float* __restrict__ Cp) {
    __shared__ __align__(16) ushort As[2][128 * 32];
    __shared__ __align__(16) ushort Bs[2][128 * 32];
    const int m0   = blockIdx.x * 128;
    const int n0   = blockIdx.y * 128;
    const int t    = threadIdx.x;
    const int w    = t >> 6;
    const int lane = t & 63;
    const int wm   = (w >> 1) * 64;
    const int wn   = (w & 1) * 64;
    const int lm   = lane & 15;
    const int quad = lane >> 4;

    auto stage = [&](ushort* dst, const ushort* src, int row0, int kc) {
        #pragma unroll
        for (int i = 0; i < 2; ++i) {
            const int c0 = (i * 4 + w) * 64;
            const int c  = c0 + lane;
            const int row = c >> 2, ko = (c & 3) * 8;
            gld16(&src[(size_t)(row0 + row) * 256 + kc + ko], dst + (size_t)c0 * 8);
        }
    };

    f32x4 acc[4][4];
    #pragma unroll
    for (int i = 0; i < 4; ++i)
        #pragma unroll
        for (int j = 0; j < 4; ++j)
            acc[i][j] = (f32x4)(0.f);

    stage(&As[0][0], A, m0, 0);
    stage(&Bs[0][0], Bt, n0, 0);
    __syncthreads();

    int cur = 0;
    for (int kc = 0; kc < 256; kc += 32) {
        const int nxt = cur ^ 1;
        bf16x8 af[4], bfr[4];
        #pragma unroll
        for (int mf = 0; mf < 4; ++mf)
            af[mf] = *(const bf16x8*)&As[cur][(wm + mf * 16 + lm) * 32 + quad * 8];
        #pragma unroll
        for (int nf = 0; nf < 4; ++nf)
            bfr[nf] = *(const bf16x8*)&Bs[cur][(wn + nf * 16 + lm) * 32 + quad * 8];
        if (kc + 32 < 256) {
            stage(&As[nxt][0], A, m0, kc + 32);
            stage(&Bs[nxt][0], Bt, n0, kc + 32);
        }
        #pragma unroll
        for (int mf = 0; mf < 4; ++mf)
            #pragma unroll
            for (int nf = 0; nf < 4; ++nf)
                acc[mf][nf] = __builtin_amdgcn_mfma_f32_16x16x32_bf16(
                    af[mf], bfr[nf], acc[mf][nf], 0, 0, 0);
        if (kc + 32 < 256) __syncthreads();
        cur = nxt;
    }

    #pragma unroll
    for (int mf = 0; mf < 4; ++mf) {
        #pragma unroll
        for (int nf = 0; nf < 4; ++nf) {
            const f32x4 a = acc[mf][nf];
            const int col   = n0 + wn + nf * 16 + lm;
            const int rbase = m0 + wm + mf * 16 + quad * 4;
            #pragma unroll
            for (int r = 0; r < 4; ++r)
                Cp[(size_t)(rbase + r) * 256 + col] = a[r] + bias[col];
        }
    }
}

// ---------------------------------------------------------------------------
extern "C" void kernel_launch(void* const* d_in, const int* in_sizes, int n_in,
                              void* d_out, int out_size, void* d_ws, size_t ws_size,
                              hipStream_t stream) {
    const float* query = (const float*)d_in[0];
    const float* refp  = (const float*)d_in[1];
    const float* value = (const float*)d_in[2];
    const float* Wt = (const float*)d_in[5];
    const float* bt = (const float*)d_in[6];
    const float* Wf = (const float*)d_in[7];
    const float* bf = (const float*)d_in[8];
    const float* Wl = (const float*)d_in[9];
    const float* bl = (const float*)d_in[10];
    const float* Wp = (const float*)d_in[11];
    const float* bp = (const float*)d_in[12];
    const float* Wv = (const float*)d_in[13];
    const float* bv = (const float*)d_in[14];
    const float* Wo = (const float*)d_in[15];
    const float* bo = (const float*)d_in[16];

    // ws layout (all offsets 16B aligned)
    char* wsb = (char*)d_ws;
    ushort* vperm  = (ushort*)wsb;                       // 12,156,928 B
    float*  params = (float*)(wsb + 12156928);           // 33,554,432 B
    ushort* midb   = (ushort*)(wsb + 45711360);          // 16,777,216 B
    ushort* Wvt    = (ushort*)(wsb + 62488576);          // 131,072 B
    ushort* Wot    = (ushort*)(wsb + 62619648);          // 131,072 B
    ushort* Wqt    = (ushort*)(wsb + 62750720);          // 147,456 B

    // weight transposes
    k_prep<<<800, 256, 0, stream>>>(Wv, Wo, Wt, Wf, Wl, Wp, Wvt, Wot, Wqt);
    // fused: vproj (340) + qproj (512) + slab border zero (62)
    k_fused<<<914, 256, 0, stream>>>(value, Wvt, bv, vperm,
                                     query, Wqt, refp, bt, bf, bl, bp, params);
    // sampling + attention -> bf16 mid (level-split, XCD-swizzled flat grid)
    k_sample<<<dim3(NQ_ / 8 * B_), 512, 0, stream>>>(vperm, params, midb);
    // output projection (bf16 A)
    k_ogemm<<<dim3(256, 2), 256, 0, stream>>>(midb, Wot, bo, (float*)d_out);
}

// Round 8
// 217.254 us; speedup vs baseline: 1.1230x; 1.0817x over previous
//
#include <hip/hip_runtime.h>
#include <math.h>

// Problem constants (match reference)
#define B_  4
#define NQ_ 8192
#define D_  256
#define H_  8
#define L_  4
#define K_  4
#define DH_ 32
#define NV_ 5440

// Padded value-slab geometry (per (b,h)): levels with 1-px zero border
// L0: 66x66=4356, L1: 34x34=1156, L2: 18x18=324, L3: 10x10=100 -> 5936 rows
#define SLAB_ 5936

typedef short bf16x8 __attribute__((ext_vector_type(8)));
typedef float f32x4  __attribute__((ext_vector_type(4)));
typedef float f32x8  __attribute__((ext_vector_type(8)));
typedef unsigned short u16x8 __attribute__((ext_vector_type(8)));

__device__ __forceinline__ ushort f2bf(float f) {
    union { float f; unsigned u; } v; v.f = f;
    return (ushort)((v.u + 0x7FFF + ((v.u >> 16) & 1)) >> 16);
}
__device__ __forceinline__ float bf2f(ushort u) {
    union { unsigned u; float f; } v; v.u = ((unsigned)u) << 16;
    return v.f;
}
// async global->LDS 16B: per-lane global addr, wave-uniform LDS base,
// lane l lands at base + l*16 (m104 semantics). Counter: vmcnt.
__device__ __forceinline__ void gld16(const void* g, void* l) {
    __builtin_amdgcn_global_load_lds(
        (const __attribute__((address_space(1))) unsigned int*)g,
        (__attribute__((address_space(3))) unsigned int*)l, 16, 0, 0);
}

// ---------------------------------------------------------------------------
// k_prep (R14): coalesced weight transposes.
//  [0,64):    Wv 32x32 LDS-tile transpose -> Wvt   (coalesced both sides)
//  [64,128):  Wo 32x32 LDS-tile transpose -> Wot
//  [128,416): {Wt|Wf|Wlv|Wp} column-gather -> Wqt (small, kept simple)
// Old form read columns at stride 1KB (one element/lane); tiles read
// float4-coalesced rows and write ushort4-coalesced rows.
// ---------------------------------------------------------------------------
__global__ __launch_bounds__(256) void k_prep(const float* __restrict__ Wv,
                                              const float* __restrict__ Wo,
                                              const float* __restrict__ Wt,
                                              const float* __restrict__ Wf,
                                              const float* __restrict__ Wlv,
                                              const float* __restrict__ Wp,
                                              ushort* __restrict__ Wvt,
                                              ushort* __restrict__ Wot,
                                              ushort* __restrict__ Wqt) {
    const int bk = blockIdx.x;
    const int t  = threadIdx.x;
    if (bk < 128) {
        __shared__ ushort tl[32][36];   // +4 pad: 72B row stride
        const float* in  = (bk < 64) ? Wv : Wo;
        ushort*      out = (bk < 64) ? Wvt : Wot;
        const int tid = bk & 63;
        const int r0 = (tid >> 3) * 32, c0 = (tid & 7) * 32;
        const int row = t >> 3, c4 = t & 7;
        const float4 v = *(const float4*)&in[(size_t)(r0 + row) * 256 + c0 + c4 * 4];
        ushort4 u;
        u.x = f2bf(v.x); u.y = f2bf(v.y); u.z = f2bf(v.z); u.w = f2bf(v.w);
        *(ushort4*)&tl[row][c4 * 4] = u;
        __syncthreads();
        const int oc = t >> 3, r4 = t & 7;
        ushort4 o;
        o.x = tl[r4 * 4 + 0][oc];
        o.y = tl[r4 * 4 + 1][oc];
        o.z = tl[r4 * 4 + 2][oc];
        o.w = tl[r4 * 4 + 3][oc];
        *(ushort4*)&out[(size_t)(c0 + oc) * 256 + r0 + r4 * 4] = o;
    } else {
        const int n = bk - 128;
        float v;
        if (n < 64)       v = Wt[t * 64 + n];
        else if (n < 128) v = Wf[t * 64 + (n - 64)];
        else if (n < 160) v = Wlv[t * 32 + (n - 128)];
        else              v = Wp[t * 128 + (n - 160)];
        Wqt[n * 256 + t] = f2bf(v);
    }
}

// ---------------------------------------------------------------------------
// vproj role: C = value[21760][256] @ Wvt[256][256]^T + bv -> bf16 padded slab
// tile 128x128, 4 waves 2x2, 16x16x32 bf16, BK=32, T3 2-phase dbuf
// ---------------------------------------------------------------------------
__device__ __forceinline__ void vproj_role(char* smem, int fid,
                                           const float* __restrict__ value,
                                           const ushort* __restrict__ Wvt,
                                           const float* __restrict__ bv,
                                           ushort* __restrict__ vperm) {
    ushort* As0 = (ushort*)smem;             // 2 bufs x 4096 ushort (16384 B)
    ushort* Bs0 = (ushort*)(smem + 16384);   // 2 bufs x 4096 ushort (16384 B)
    const int m0   = (fid % 170) * 128;
    const int n0   = (fid / 170) * 128;
    const int t    = threadIdx.x;
    const int w    = t >> 6;
    const int lane = t & 63;
    const int wm   = (w >> 1) * 64;
    const int wn   = (w & 1) * 64;
    const int lm   = lane & 15;
    const int quad = lane >> 4;

    float4 areg[4];

    auto stageB = [&](int buf, int kc) {
        ushort* B = Bs0 + buf * 4096;
        #pragma unroll
        for (int i = 0; i < 2; ++i) {
            const int c0 = (i * 4 + w) * 64;
            const int c  = c0 + lane;
            const int row = c >> 2, ko = (c & 3) * 8;
            gld16(&Wvt[(size_t)(n0 + row) * 256 + kc + ko], B + (size_t)c0 * 8);
        }
    };
    auto loadA = [&](int kc) {
        #pragma unroll
        for (int i = 0; i < 4; ++i) {
            const int c = t + i * 256;
            const int row = c >> 3, ko = (c & 7) * 4;
            areg[i] = *(const float4*)&value[(size_t)(m0 + row) * 256 + kc + ko];
        }
    };
    auto writeA = [&](int buf) {
        ushort* A = As0 + buf * 4096;
        #pragma unroll
        for (int i = 0; i < 4; ++i) {
            const int c = t + i * 256;
            const int row = c >> 3, ko = (c & 7) * 4;
            ushort4 u;
            u.x = f2bf(areg[i].x); u.y = f2bf(areg[i].y);
            u.z = f2bf(areg[i].z); u.w = f2bf(areg[i].w);
            *(ushort4*)&A[row * 32 + ko] = u;
        }
    };

    f32x4 acc[4][4];
    #pragma unroll
    for (int i = 0; i < 4; ++i)
        #pragma unroll
        for (int j = 0; j < 4; ++j)
            acc[i][j] = (f32x4)(0.f);

    loadA(0); writeA(0);
    stageB(0, 0);
    __syncthreads();

    int cur = 0;
    for (int kc = 0; kc < 256; kc += 32) {
        const int nxt = cur ^ 1;
        const ushort* Ac = As0 + cur * 4096;
        const ushort* Bc = Bs0 + cur * 4096;
        bf16x8 af[4], bfr[4];
        #pragma unroll
        for (int mf = 0; mf < 4; ++mf)
            af[mf] = *(const bf16x8*)&Ac[(wm + mf * 16 + lm) * 32 + quad * 8];
        #pragma unroll
        for (int nf = 0; nf < 4; ++nf)
            bfr[nf] = *(const bf16x8*)&Bc[(wn + nf * 16 + lm) * 32 + quad * 8];
        if (kc + 32 < 256) {
            loadA(kc + 32);
            stageB(nxt, kc + 32);
        }
        #pragma unroll
        for (int mf = 0; mf < 4; ++mf)
            #pragma unroll
            for (int nf = 0; nf < 4; ++nf)
                acc[mf][nf] = __builtin_amdgcn_mfma_f32_16x16x32_bf16(
                    af[mf], bfr[nf], acc[mf][nf], 0, 0, 0);
        if (kc + 32 < 256) {
            writeA(nxt);
            __syncthreads();
        }
        cur = nxt;
    }

    // epilogue: bf16 padded slab write (zero-border layout)
    #pragma unroll
    for (int mf = 0; mf < 4; ++mf) {
        #pragma unroll
        for (int nf = 0; nf < 4; ++nf) {
            const f32x4 a = acc[mf][nf];
            const int col   = n0 + wn + nf * 16 + lm;
            const int rbase = m0 + wm + mf * 16 + quad * 4;
            #pragma unroll
            for (int r = 0; r < 4; ++r) {
                const int row = rbase + r;
                const float v = a[r];
                const int b = row / NV_, s = row - b * NV_;
                const int h = col >> 5, dh = col & 31;
                const int l = (s >= 5376) ? 3 : (s >= 5120) ? 2 : (s >= 4096) ? 1 : 0;
                const int lsi_[4] = {0, 4096, 5120, 5376};
                const int po_[4]  = {0, 4356, 5512, 5836};
                const int o  = s - lsi_[l];
                const int Wl = 64 >> l;
                const int y  = o >> (6 - l);
                const int x  = o & (Wl - 1);
                const int prow = po_[l] + (y + 1) * (Wl + 2) + (x + 1);
                vperm[(((size_t)(b * H_ + h)) * SLAB_ + prow) * 32 + dh] =
                    f2bf(v + bv[col]);
            }
        }
    }
}

// ---------------------------------------------------------------------------
// qproj role: query f32 -> params (fused tanh/softmax/coords epilogue)
// tile M=64 x N=288, 4 waves 2x2 (wm {0,32}, wn {0,144}), BK=32, 2-phase dbuf
// ---------------------------------------------------------------------------
__device__ __forceinline__ void qproj_role(char* smem, int fid,
                                           const float* __restrict__ query,
                                           const ushort* __restrict__ Wqt,
                                           const float* __restrict__ refpts,
                                           const float* __restrict__ bt,
                                           const float* __restrict__ bfq,
                                           const float* __restrict__ blv,
                                           const float* __restrict__ bp,
                                           float* __restrict__ params) {
    ushort* As0 = (ushort*)smem;            // 2 bufs x 2048 ushort
    ushort* Bs0 = (ushort*)(smem + 8192);   // 2 bufs x 9216 ushort
    float*  ep  = (float*)smem;             // epilogue alias (37888 B)

    const int m0   = fid * 64;
    const int t    = threadIdx.x;
    const int w    = t >> 6;
    const int lane = t & 63;
    const int wm   = (w >> 1) * 32;
    const int wn   = (w & 1) * 144;
    const int lm   = lane & 15;
    const int quad = lane >> 4;

    float4 areg[2];

    auto stageB = [&](int buf, int kc) {
        ushort* B = Bs0 + buf * 9216;
        #pragma unroll
        for (int i = 0; i < 5; ++i) {
            const int cb = i * 4 + w;
            if (cb < 18) {
                const int c0 = cb * 64;
                const int c  = c0 + lane;
                const int row = c >> 2, ko = (c & 3) * 8;
                gld16(&Wqt[(size_t)row * 256 + kc + ko], B + (size_t)c0 * 8);
            }
        }
    };
    auto loadA = [&](int kc) {
        #pragma unroll
        for (int i = 0; i < 2; ++i) {
            const int c = t + i * 256;
            const int row = c >> 3, ko = (c & 7) * 4;
            areg[i] = *(const float4*)&query[(size_t)(m0 + row) * 256 + kc + ko];
        }
    };
    auto writeA = [&](int buf) {
        ushort* A = As0 + buf * 2048;
        #pragma unroll
        for (int i = 0; i < 2; ++i) {
            const int c = t + i * 256;
            const int row = c >> 3, ko = (c & 7) * 4;
            ushort4 u;
            u.x = f2bf(areg[i].x); u.y = f2bf(areg[i].y);
            u.z = f2bf(areg[i].z); u.w = f2bf(areg[i].w);
            *(ushort4*)&A[row * 32 + ko] = u;
        }
    };

    f32x4 acc[2][9];
    #pragma unroll
    for (int i = 0; i < 2; ++i)
        #pragma unroll
        for (int j = 0; j < 9; ++j)
            acc[i][j] = (f32x4)(0.f);

    loadA(0); writeA(0);
    stageB(0, 0);
    __syncthreads();

    int cur = 0;
    for (int kc = 0; kc < 256; kc += 32) {
        const int nxt = cur ^ 1;
        const ushort* Ac = As0 + cur * 2048;
        const ushort* Bc = Bs0 + cur * 9216;
        bf16x8 af[2], bfr[9];
        #pragma unroll
        for (int mf = 0; mf < 2; ++mf)
            af[mf] = *(const bf16x8*)&Ac[(wm + mf * 16 + lm) * 32 + quad * 8];
        #pragma unroll
        for (int nf = 0; nf < 9; ++nf)
            bfr[nf] = *(const bf16x8*)&Bc[(wn + nf * 16 + lm) * 32 + quad * 8];
        if (kc + 32 < 256) {
            loadA(kc + 32);
            stageB(nxt, kc + 32);
        }
        #pragma unroll
        for (int mf = 0; mf < 2; ++mf)
            #pragma unroll
            for (int nf = 0; nf < 9; ++nf)
                acc[mf][nf] = __builtin_amdgcn_mfma_f32_16x16x32_bf16(
                    af[mf], bfr[nf], acc[mf][nf], 0, 0, 0);
        if (kc + 32 < 256) {
            writeA(nxt);
            __syncthreads();
        }
        cur = nxt;
    }

    // fused epilogue: two phases of 32 q-rows through LDS
    #pragma unroll
    for (int ph = 0; ph < 2; ++ph) {
        __syncthreads();
        if ((w >> 1) == ph) {
            #pragma unroll
            for (int mf = 0; mf < 2; ++mf)
                #pragma unroll
                for (int nf = 0; nf < 9; ++nf)
                    #pragma unroll
                    for (int r = 0; r < 4; ++r)
                        ep[(mf * 16 + quad * 4 + r) * 296 + wn + nf * 16 + lm]
                            = acc[mf][nf][r];
        }
        __syncthreads();
        #pragma unroll
        for (int it = 0; it < 4; ++it) {
            const int item = t + it * 256;
            const int qr = item >> 5;
            const int hl = item & 31;
            const int h = hl >> 2, l = hl & 3;
            const int qg = m0 + ph * 32 + qr;
            const float* lgr = &ep[qr * 296];

            const float tA = tanhf(lgr[hl * 2 + 0] + bt[hl * 2 + 0]);
            const float tB = tanhf(lgr[hl * 2 + 1] + bt[hl * 2 + 1]);
            const float fA = tanhf(lgr[64 + hl * 2 + 0] + bfq[hl * 2 + 0]);
            const float fB = tanhf(lgr[64 + hl * 2 + 1] + bfq[hl * 2 + 1]);

            const float l0 = lgr[128 + h * 4 + 0] + blv[h * 4 + 0];
            const float l1 = lgr[128 + h * 4 + 1] + blv[h * 4 + 1];
            const float l2 = lgr[128 + h * 4 + 2] + blv[h * 4 + 2];
            const float l3 = lgr[128 + h * 4 + 3] + blv[h * 4 + 3];
            const float lmx = fmaxf(fmaxf(l0, l1), fmaxf(l2, l3));
            const float e0 = __expf(l0 - lmx), e1 = __expf(l1 - lmx);
            const float e2 = __expf(l2 - lmx), e3 = __expf(l3 - lmx);
            const float lsum = e0 + e1 + e2 + e3;
            const float lwv = ((l == 0) ? e0 : (l == 1) ? e1 : (l == 2) ? e2 : e3) / lsum;

            const float p0 = lgr[160 + hl * 4 + 0] + bp[hl * 4 + 0];
            const float p1 = lgr[160 + hl * 4 + 1] + bp[hl * 4 + 1];
            const float p2 = lgr[160 + hl * 4 + 2] + bp[hl * 4 + 2];
            const float p3 = lgr[160 + hl * 4 + 3] + bp[hl * 4 + 3];
            const float pmx = fmaxf(fmaxf(p0, p1), fmaxf(p2, p3));
            const float q0e = __expf(p0 - pmx), q1e = __expf(p1 - pmx);
            const float q2e = __expf(p2 - pmx), q3e = __expf(p3 - pmx);
            const float inv = lwv / (q0e + q1e + q2e + q3e);

            const float rx = refpts[((size_t)qg * L_ + l) * 2 + 0];
            const float ry = refpts[((size_t)qg * L_ + l) * 2 + 1];
            const float Wlf = (float)(64 >> l);
            const float Hlf = (float)(64 >> l);
            const float xA = fminf(fmaxf(rx + tA / Wlf, 0.f), 1.f) * Wlf - 0.5f;
            const float xB = fminf(fmaxf(rx + tB / Wlf, 0.f), 1.f) * Wlf - 0.5f;
            const float yA = fminf(fmaxf(ry + fA / Hlf, 0.f), 1.f) * Hlf - 0.5f;
            const float yB = fminf(fmaxf(ry + fB / Hlf, 0.f), 1.f) * Hlf - 0.5f;

            float* pp = params + (size_t)qg * 256 + hl * 8;
            pp[0] = q0e * inv; pp[1] = q1e * inv; pp[2] = q2e * inv; pp[3] = q3e * inv;
            pp[4] = xA; pp[5] = xB; pp[6] = yA; pp[7] = yB;
        }
    }
}

// ---------------------------------------------------------------------------
// border role: zero the 1-px slab borders (the only part vproj doesn't write).
// ---------------------------------------------------------------------------
__device__ __forceinline__ void border_role(int fid, ushort* __restrict__ vperm) {
    const int t = threadIdx.x;
    const int p = fid * 256 + t;           // [0, 15872)
    const int bh = p / 496;
    int e = p - bh * 496;                  // cum borders: 260,392,460,496
    int l = 0;
    if (e >= 460)      { l = 3; e -= 460; }
    else if (e >= 392) { l = 2; e -= 392; }
    else if (e >= 260) { l = 1; e -= 260; }
    const int po_[4] = {0, 4356, 5512, 5836};
    const int W2 = (64 >> l) + 2;
    int row, col;
    if (e < 2 * W2) {
        row = (e < W2) ? 0 : (W2 - 1);
        col = (e < W2) ? e : (e - W2);
    } else {
        const int e2 = e - 2 * W2;
        row = 1 + (e2 >> 1);
        col = (e2 & 1) ? (W2 - 1) : 0;
    }
    uint4* dst = (uint4*)&vperm[((size_t)bh * SLAB_ + po_[l] + row * W2 + col) * 32];
    dst[0] = make_uint4(0, 0, 0, 0);
    dst[1] = make_uint4(0, 0, 0, 0);
    dst[2] = make_uint4(0, 0, 0, 0);
    dst[3] = make_uint4(0, 0, 0, 0);
}

// ---------------------------------------------------------------------------
// k_fused: vproj + qproj + border-zero in ONE launch.
//  [0,340):   vproj tiles (170 x 2)
//  [340,852): qproj tiles (512)
//  [852,914): border zeroing
// ---------------------------------------------------------------------------
__global__ __launch_bounds__(256) void k_fused(const float* __restrict__ value,
                                               const ushort* __restrict__ Wvt,
                                               const float* __restrict__ bv,
                                               ushort* __restrict__ vperm,
                                               const float* __restrict__ query,
                                               const ushort* __restrict__ Wqt,
                                               const float* __restrict__ refpts,
                                               const float* __restrict__ bt,
                                               const float* __restrict__ bfq,
                                               const float* __restrict__ blv,
                                               const float* __restrict__ bp,
                                               float* __restrict__ params) {
    __shared__ __align__(16) char smem[45056];
    const int fid = blockIdx.x;
    if (fid < 340) {
        vproj_role(smem, fid, value, Wvt, bv, vperm);
    } else if (fid < 852) {
        qproj_role(smem, fid - 340, query, Wqt, refpts, bt, bfq, blv, bp, params);
    } else {
        border_role(fid - 852, vperm);
    }
}

// ---------------------------------------------------------------------------
// k_sample: bilinear sampling + attention -> bf16 mid. EXACT R1 form, frozen:
// thread = (ql, h, dh8), 256 threads / 8 queries, VGPR 120 keeps a whole
// level's 16 gathers in flight. Three restructures all regressed:
//   pk_fma (R2, VGPR 40): 58.5->63.6; out-proj fusion (R5/R6): 88.8/97.6;
//   level-split shfl (R7, VGPR 68): 72.9. Per-wave MLP window is the binding
//   constraint; do not reduce register pressure here.
// XCD swizzle: b=(fid&7)>>1 -> one batch slab per XCD (FETCH 61->34.9 MB).
// ---------------------------------------------------------------------------
__global__ __launch_bounds__(256) void k_sample(const ushort* __restrict__ vperm,
                                                const float* __restrict__ params,
                                                ushort* __restrict__ mid) {
    __shared__ float pm[8][264];   // per q: [h][33] padded
    const int fid = blockIdx.x;
    const int b   = (fid & 7) >> 1;
    const int q0  = (((fid >> 3) << 1) | (fid & 1)) * 8;
    const int t   = threadIdx.x;
    const int ql  = t >> 5;
    const int sub = t & 31;
    const int h   = sub >> 2;
    const int dh8 = sub & 3;

    for (int i = t; i < 8 * 256; i += 256) {
        const int q = i >> 8, c = i & 255;
        pm[q][(c >> 5) * 33 + (c & 31)] = params[((size_t)(b * NQ_ + q0 + q)) * 256 + c];
    }
    __syncthreads();

    const ushort* vb = vperm + ((size_t)(b * H_ + h)) * SLAB_ * 32 + dh8 * 8;
    const int po_[4] = {0, 4356, 5512, 5836};

    f32x8 acc = (f32x8)(0.f);
    #pragma unroll
    for (int l = 0; l < L_; ++l) {
        const int W2 = (64 >> l) + 2;
        const ushort* vl = vb + (size_t)po_[l] * 32;
        const float* p  = &pm[ql][h * 33 + l * 8];
        const float a0 = p[0], a1 = p[1], a2 = p[2], a3 = p[3];
        const float xA = p[4], xB = p[5], yA = p[6], yB = p[7];
        const float xa0 = floorf(xA), xb0 = floorf(xB);
        const float ya0 = floorf(yA), yb0 = floorf(yB);
        const float fxa = xA - xa0, fxb = xB - xb0;
        const float fya = yA - ya0, fyb = yB - yb0;
        const int pxa = (int)xa0 + 1, pxb = (int)xb0 + 1;
        const int pya = (int)ya0 + 1, pyb = (int)yb0 + 1;
        #pragma unroll
        for (int k = 0; k < 4; ++k) {
            const int   px = (k & 2) ? pxb : pxa;
            const int   py = (k & 1) ? pyb : pya;
            const float fx = (k & 2) ? fxb : fxa;
            const float fy = (k & 1) ? fyb : fya;
            const float ak = (k == 0) ? a0 : (k == 1) ? a1 : (k == 2) ? a2 : a3;
            const ushort* cp = vl + (size_t)(py * W2 + px) * 32;
            const u16x8 u00 = *(const u16x8*)cp;
            const u16x8 u10 = *(const u16x8*)(cp + 32);
            const u16x8 u01 = *(const u16x8*)(cp + W2 * 32);
            const u16x8 u11 = *(const u16x8*)(cp + (W2 + 1) * 32);
            const float gx = 1.f - fx, gy = 1.f - fy;
            const float w00 = ak * gx * gy, w10 = ak * fx * gy;
            const float w01 = ak * gx * fy, w11 = ak * fx * fy;
            #pragma unroll
            for (int e = 0; e < 8; ++e)
                acc[e] += bf2f(u00[e]) * w00 + bf2f(u10[e]) * w10
                        + bf2f(u01[e]) * w01 + bf2f(u11[e]) * w11;
        }
    }
    u16x8 o;
    #pragma unroll
    for (int e = 0; e < 8; ++e) o[e] = f2bf(acc[e]);
    *(u16x8*)&mid[((size_t)(b * NQ_ + q0 + ql)) * 256 + sub * 8] = o;
}

// ---------------------------------------------------------------------------
// out projection (R14): C = mid @ Wot^T + bo. tile 128x128, BK=64 (4 K-steps,
// half the barriers of BK=32, 2x in-flight gld16 per stage -- ogemm runs at
// only 2 blocks/CU so per-wave MLP is its latency lever). LDS 64 KB.
// ---------------------------------------------------------------------------
__global__ __launch_bounds__(256) void k_ogemm(const ushort* __restrict__ A,
                                               const ushort* __restrict__ Bt,
                                               const float* __restrict__ bias,
                                               float* __restrict__ Cp) {
    __shared__ __align__(16) ushort As[2][128 * 64];
    __shared__ __align__(16) ushort Bs[2][128 * 64];
    const int m0   = blockIdx.x * 128;
    const int n0   = blockIdx.y * 128;
    const int t    = threadIdx.x;
    const int w    = t >> 6;
    const int lane = t & 63;
    const int wm   = (w >> 1) * 64;
    const int wn   = (w & 1) * 64;
    const int lm   = lane & 15;
    const int quad = lane >> 4;

    // 128 rows x 64 k = 1024 16B chunks per operand, 4/thread
    auto stage = [&](ushort* dst, const ushort* src, int row0, int kc) {
        #pragma unroll
        for (int i = 0; i < 4; ++i) {
            const int c0 = (i * 4 + w) * 64;
            const int c  = c0 + lane;
            const int row = c >> 3, ko = (c & 7) * 8;
            gld16(&src[(size_t)(row0 + row) * 256 + kc + ko], dst + (size_t)c0 * 8);
        }
    };

    f32x4 acc[4][4];
    #pragma unroll
    for (int i = 0; i < 4; ++i)
        #pragma unroll
        for (int j = 0; j < 4; ++j)
            acc[i][j] = (f32x4)(0.f);

    stage(&As[0][0], A, m0, 0);
    stage(&Bs[0][0], Bt, n0, 0);
    __syncthreads();

    int cur = 0;
    for (int kc = 0; kc < 256; kc += 64) {
        const int nxt = cur ^ 1;
        if (kc + 64 < 256) {
            stage(&As[nxt][0], A, m0, kc + 64);
            stage(&Bs[nxt][0], Bt, n0, kc + 64);
        }
        #pragma unroll
        for (int kk = 0; kk < 64; kk += 32) {
            bf16x8 af[4], bfr[4];
            #pragma unroll
            for (int mf = 0; mf < 4; ++mf)
                af[mf] = *(const bf16x8*)&As[cur][(wm + mf * 16 + lm) * 64 + kk + quad * 8];
            #pragma unroll
            for (int nf = 0; nf < 4; ++nf)
                bfr[nf] = *(const bf16x8*)&Bs[cur][(wn + nf * 16 + lm) * 64 + kk + quad * 8];
            #pragma unroll
            for (int mf = 0; mf < 4; ++mf)
                #pragma unroll
                for (int nf = 0; nf < 4; ++nf)
                    acc[mf][nf] = __builtin_amdgcn_mfma_f32_16x16x32_bf16(
                        af[mf], bfr[nf], acc[mf][nf], 0, 0, 0);
        }
        if (kc + 64 < 256) __syncthreads();
        cur = nxt;
    }

    #pragma unroll
    for (int mf = 0; mf < 4; ++mf) {
        #pragma unroll
        for (int nf = 0; nf < 4; ++nf) {
            const f32x4 a = acc[mf][nf];
            const int col   = n0 + wn + nf * 16 + lm;
            const int rbase = m0 + wm + mf * 16 + quad * 4;
            #pragma unroll
            for (int r = 0; r < 4; ++r)
                Cp[(size_t)(rbase + r) * 256 + col] = a[r] + bias[col];
        }
    }
}

// ---------------------------------------------------------------------------
extern "C" void kernel_launch(void* const* d_in, const int* in_sizes, int n_in,
                              void* d_out, int out_size, void* d_ws, size_t ws_size,
                              hipStream_t stream) {
    const float* query = (const float*)d_in[0];
    const float* refp  = (const float*)d_in[1];
    const float* value = (const float*)d_in[2];
    const float* Wt = (const float*)d_in[5];
    const float* bt = (const float*)d_in[6];
    const float* Wf = (const float*)d_in[7];
    const float* bf = (const float*)d_in[8];
    const float* Wl = (const float*)d_in[9];
    const float* bl = (const float*)d_in[10];
    const float* Wp = (const float*)d_in[11];
    const float* bp = (const float*)d_in[12];
    const float* Wv = (const float*)d_in[13];
    const float* bv = (const float*)d_in[14];
    const float* Wo = (const float*)d_in[15];
    const float* bo = (const float*)d_in[16];

    // ws layout (all offsets 16B aligned)
    char* wsb = (char*)d_ws;
    ushort* vperm  = (ushort*)wsb;                       // 12,156,928 B
    float*  params = (float*)(wsb + 12156928);           // 33,554,432 B
    ushort* midb   = (ushort*)(wsb + 45711360);          // 16,777,216 B
    ushort* Wvt    = (ushort*)(wsb + 62488576);          // 131,072 B
    ushort* Wot    = (ushort*)(wsb + 62619648);          // 131,072 B
    ushort* Wqt    = (ushort*)(wsb + 62750720);          // 147,456 B

    // weight transposes (coalesced LDS tiles for Wv/Wo)
    k_prep<<<416, 256, 0, stream>>>(Wv, Wo, Wt, Wf, Wl, Wp, Wvt, Wot, Wqt);
    // fused: vproj (340) + qproj (512) + slab border zero (62)
    k_fused<<<914, 256, 0, stream>>>(value, Wvt, bv, vperm,
                                     query, Wqt, refp, bt, bf, bl, bp, params);
    // sampling + attention -> bf16 mid (R1-frozen form, XCD-swizzled)
    k_sample<<<dim3(NQ_ / 8 * B_), 256, 0, stream>>>(vperm, params, midb);
    // output projection (BK=64)
    k_ogemm<<<dim3(256, 2), 256, 0, stream>>>(midb, Wot, bo, (float*)d_out);
}